// Round 9
// baseline (927.614 us; speedup 1.0000x reference)
//
#include <hip/hip_runtime.h>
#include <hip/hip_bf16.h>
#include <math.h>

using bf16 = __hip_bfloat16;
typedef __attribute__((ext_vector_type(8))) short short8;
typedef __attribute__((ext_vector_type(4))) float f32x4;

__device__ __forceinline__ float tof(float x) { return x; }
__device__ __forceinline__ float tof(bf16 x) { return __bfloat162float(x); }
__device__ __forceinline__ float b2f(unsigned short u) {
  union { float f; unsigned int i; } c; c.i = ((unsigned int)u) << 16; return c.f;
}
__device__ __forceinline__ unsigned short f2bu(float v) {
  bf16 h = __float2bfloat16(v);
  return *(unsigned short*)&h;
}
__device__ __forceinline__ void sto1(float* p, float v) { *p = v; }
__device__ __forceinline__ void sto1(bf16* p, float v) { *p = __float2bfloat16(v); }

__device__ __forceinline__ float gelu_exact(float x) {
  return 0.5f * x * (1.f + erff(x * 0.70710678118654752f));
}

// async global->LDS, 16B/lane; LDS dest = wave base + lane*16 (m97 pattern).
__device__ __forceinline__ void llds16(const bf16* g, short* l) {
  __builtin_amdgcn_global_load_lds((const __attribute__((address_space(1))) void*)g,
                                   (__attribute__((address_space(3))) void*)l, 16, 0, 0);
}

// ---------------------------------------------------------------------------
// Weight conversion (once per launch; small).
// ---------------------------------------------------------------------------
__global__ __launch_bounds__(256) void pack_qkv_kernel(
    const float* __restrict__ wq, const float* __restrict__ wk,
    const float* __restrict__ wv, bf16* __restrict__ out)
{
  int idx = blockIdx.x * 256 + threadIdx.x;   // < 4*768*256
  int k = idx & 255;
  int nl = idx >> 8;
  int n = nl % 768, l = nl / 768;
  const float* src = (n < 256) ? wq : (n < 512 ? wk : wv);
  out[idx] = __float2bfloat16(src[(long)l * 65536 + k * 256 + (n & 255)]);
}

__global__ __launch_bounds__(256) void pack_qkvbias_kernel(
    const float* __restrict__ bq, const float* __restrict__ bk,
    const float* __restrict__ bv, float* __restrict__ out)
{
  int i = blockIdx.x * 256 + threadIdx.x;   // < 3072
  if (i >= 3072) return;
  int n = i % 768, l = i / 768;
  const float* src = (n < 256) ? bq : (n < 512 ? bk : bv);
  out[i] = src[l * 256 + (n & 255)];
}

// out[l][n][k] = in[l][k][n], bf16
__global__ __launch_bounds__(256) void tconv_kernel(
    const float* __restrict__ in, bf16* __restrict__ out,
    int K, int N, long sin, long sout)
{
  int l = blockIdx.z;
  int idx = blockIdx.x * 256 + threadIdx.x;
  int k = idx % K, n = idx / K;
  out[l * sout + idx] = __float2bfloat16(in[l * sin + (long)k * N + n]);
}

__global__ __launch_bounds__(256) void f2b_kernel(
    const float* __restrict__ in, bf16* __restrict__ out, int n)
{
  int i = blockIdx.x * 256 + threadIdx.x;
  if (i < n) out[i] = __float2bfloat16(in[i]);
}

__global__ __launch_bounds__(256) void zero4_kernel(float* __restrict__ p) {
  int i = (blockIdx.x * 256 + threadIdx.x) * 4;
  float4 z; z.x = 0.f; z.y = 0.f; z.z = 0.f; z.w = 0.f;
  *(float4*)&p[i] = z;
}

// s = x1 + x2, bf16 (classifier input)
__global__ __launch_bounds__(256) void sumb_kernel(
    const float* __restrict__ a, const float* __restrict__ b, bf16* __restrict__ o)
{
  int i = (blockIdx.x * 256 + threadIdx.x) * 4;
  float4 x = *(const float4*)&a[i];
  float4 y = *(const float4*)&b[i];
  ushort4 p;
  p.x = f2bu(x.x + y.x); p.y = f2bu(x.y + y.y);
  p.z = f2bu(x.z + y.z); p.w = f2bu(x.w + y.w);
  *(ushort4*)((unsigned short*)o + i) = p;
}

// ---------------------------------------------------------------------------
// Conv frontend stage 1: conv0+dw1+pw1+bn1+relu -> A1[b][t][f][ci] bf16
// ---------------------------------------------------------------------------
__global__ __launch_bounds__(256) void front1_kernel(
    const float* __restrict__ x, const float* __restrict__ c0w,
    const float* __restrict__ d1w, const float* __restrict__ d1b,
    const float* __restrict__ p1w, const float* __restrict__ p1b,
    const float* __restrict__ g1, const float* __restrict__ b1,
    const float* __restrict__ m1, const float* __restrict__ v1,
    bf16* __restrict__ A1)
{
  __shared__ float sd[256];
  __shared__ float spw[512];
  __shared__ float ss[128], st[128], sb[128];
  int tid = threadIdx.x;
  int bt = blockIdx.x;
  int b = bt >> 11, t = bt & 2047;
  if (tid < 128) {
    float s = g1[tid] * rsqrtf(v1[tid] + 1e-5f);
    ss[tid] = s;
    st[tid] = b1[tid] - m1[tid] * s;
    sb[tid] = p1b[tid];
#pragma unroll
    for (int c = 0; c < 4; ++c) spw[c * 128 + tid] = p1w[tid * 4 + c];
  }
  {
    int c = tid >> 6, f = tid & 63;
    float cw = c0w[c];
    float acc = d1b[c];
#pragma unroll
    for (int kh = 0; kh < 3; ++kh) {
      int fi = f + kh - 1;
      if (fi < 0 || fi >= 64) continue;
#pragma unroll
      for (int kw = 0; kw < 3; ++kw) {
        int ti = t + kw - 1;
        if (ti < 0 || ti >= 2048) continue;
        acc += d1w[c * 9 + kh * 3 + kw] * cw * x[((long)b * 2048 + ti) * 64 + fi];
      }
    }
    sd[c * 64 + f] = acc;
  }
  __syncthreads();
  long ob = (long)bt * 8192;
  for (int it = 0; it < 32; ++it) {
    int o = it * 256 + tid;
    int f = o >> 7, ci = o & 127;
    float pre = sb[ci];
#pragma unroll
    for (int c = 0; c < 4; ++c) pre = fmaf(spw[c * 128 + ci], sd[c * 64 + f], pre);
    A1[ob + o] = __float2bfloat16(fmaxf(fmaf(ss[ci], pre, st[ci]), 0.f));
  }
}

// ---------------------------------------------------------------------------
// Conv tail: dw2 (VALU, ci8 per thread, 16B taps) + pw2 (MFMA) + bn2 + relu +
// mean(f) -> hconvb bf16.  One block per (b,t).  LDS 39.4 KB -> 4 blocks/CU.
// ---------------------------------------------------------------------------
__global__ __launch_bounds__(256, 4) void convtail_kernel(
    const bf16* __restrict__ A1, const float* __restrict__ w,
    const float* __restrict__ wb, const bf16* __restrict__ w2b,
    const float* __restrict__ pb, const float* __restrict__ g2,
    const float* __restrict__ b2, const float* __restrict__ m2,
    const float* __restrict__ v2, bf16* __restrict__ hconvb)
{
  __shared__ short dw2s[64 * 136];
  __shared__ short Bs[64 * 136];
  __shared__ float red[1024];
  __shared__ float ssc[64], ssh[64];
  int tid = threadIdx.x;
  int lane = tid & 63, wv = tid >> 6;
  int quad = lane >> 4, l15 = lane & 15;
  int rw = (wv >> 1) * 32, cw = (wv & 1) * 32;
  int bt = blockIdx.x, b = bt >> 11, t = bt & 2047;
  int ci8 = (tid & 15) * 8;
  // per-thread dw2 weights / bias in registers (ci8 invariant across passes)
  float wreg[9][8], breg[8];
#pragma unroll
  for (int c = 0; c < 8; ++c) {
    breg[c] = wb[ci8 + c];
#pragma unroll
    for (int kk = 0; kk < 9; ++kk) wreg[kk][c] = w[(ci8 + c) * 9 + kk];
  }
  const unsigned short* A1u = (const unsigned short*)A1;
  for (int pass = 0; pass < 4; ++pass) {
    int f = pass * 16 + (tid >> 4);
    float a[8];
#pragma unroll
    for (int c = 0; c < 8; ++c) a[c] = breg[c];
#pragma unroll
    for (int kh = 0; kh < 3; ++kh) {
      int fi = f + kh - 1;
      if (fi < 0 || fi >= 64) continue;
#pragma unroll
      for (int kw = 0; kw < 3; ++kw) {
        int ti = t + kw - 1;
        if (ti < 0 || ti >= 2048) continue;
        short8 u = *(const short8*)&A1u[(((long)b * 2048 + ti) * 64 + fi) * 128 + ci8];
        int kk = kh * 3 + kw;
#pragma unroll
        for (int c = 0; c < 8; ++c)
          a[c] = fmaf(wreg[kk][c], b2f((unsigned short)u[c]), a[c]);
      }
    }
    short8 p;
#pragma unroll
    for (int c = 0; c < 8; ++c) p[c] = (short)f2bu(a[c]);
    *(short8*)&dw2s[f * 136 + ci8] = p;
  }
  for (int ct = 0; ct < 4; ++ct) {
    int co0 = ct * 64;
    __syncthreads();   // dw2s ready (ct=0) / red consumed (ct>0)
    for (int l2 = 0; l2 < 4; ++l2) {
      int idx = l2 * 256 + tid;
      int row = idx >> 4, koff = (idx & 15) * 8;
      *(short8*)&Bs[row * 136 + koff] =
          *(const short8*)&w2b[(long)(co0 + row) * 128 + koff];
    }
    if (tid < 64) {
      int co = co0 + tid;
      float s = g2[co] * rsqrtf(v2[co] + 1e-5f);
      ssc[tid] = s;
      ssh[tid] = b2[co] - m2[co] * s + s * pb[co];
    }
    __syncthreads();
    f32x4 zv = {0.f, 0.f, 0.f, 0.f};
    f32x4 acc[2][2] = {{zv, zv}, {zv, zv}};
#pragma unroll
    for (int kc = 0; kc < 4; ++kc) {
      short8 a0 = *(const short8*)&dw2s[(rw + l15) * 136 + kc * 32 + quad * 8];
      short8 a1 = *(const short8*)&dw2s[(rw + 16 + l15) * 136 + kc * 32 + quad * 8];
      short8 b0 = *(const short8*)&Bs[(cw + l15) * 136 + kc * 32 + quad * 8];
      short8 b1 = *(const short8*)&Bs[(cw + 16 + l15) * 136 + kc * 32 + quad * 8];
      acc[0][0] = __builtin_amdgcn_mfma_f32_16x16x32_bf16(a0, b0, acc[0][0], 0, 0, 0);
      acc[0][1] = __builtin_amdgcn_mfma_f32_16x16x32_bf16(a0, b1, acc[0][1], 0, 0, 0);
      acc[1][0] = __builtin_amdgcn_mfma_f32_16x16x32_bf16(a1, b0, acc[1][0], 0, 0, 0);
      acc[1][1] = __builtin_amdgcn_mfma_f32_16x16x32_bf16(a1, b1, acc[1][1], 0, 0, 0);
    }
#pragma unroll
    for (int mi = 0; mi < 2; ++mi)
#pragma unroll
      for (int nj = 0; nj < 2; ++nj) {
        int colg = cw + nj * 16 + l15;
        float s = ssc[colg], sh = ssh[colg];
        float sum = 0.f;
#pragma unroll
        for (int r = 0; r < 4; ++r) sum += fmaxf(fmaf(s, acc[mi][nj][r], sh), 0.f);
        int rowgroup = (wv >> 1) * 8 + mi * 4 + quad;
        red[rowgroup * 64 + colg] = sum;
      }
    __syncthreads();
    if (tid < 64) {
      float s = 0.f;
#pragma unroll
      for (int r = 0; r < 16; ++r) s += red[r * 64 + tid];
      hconvb[(long)bt * 256 + co0 + tid] = __float2bfloat16(s * (1.f / 64.f));
    }
  }
}

// ---------------------------------------------------------------------------
// FAVOR feature kernel (fused qf + kfT): F = relu(dn * X @ pm^T) + 1e-3.
// grid (32, 6, 16): z<8 -> q head z, row-layout qf[z][t][j];
//                   z>=8 -> k head z-8, transposed kfT[z][j][t] + ksum atomics.
// NOTE: kfT head stride is 786432 bf16 ELEMENTS (r5-r7 used byte strides here
// by mistake -> heads landed at 2x offsets; readers saw poison-constant kf and
// FAVOR degenerated to mean-pooling that numerically squeaked past threshold).
// ---------------------------------------------------------------------------
__global__ __launch_bounds__(256) void favor_kernel(
    const bf16* __restrict__ qkvb, const bf16* __restrict__ pm,
    bf16* __restrict__ qf, bf16* __restrict__ kfT, float* __restrict__ ksum,
    float dn)
{
  __shared__ short As[4096];
  __shared__ short Bs[4096];
  int tid = threadIdx.x;
  int lane = tid & 63, w = tid >> 6;
  int quad = lane >> 4, l15 = lane & 15;
  int rw = (w >> 1) * 32, cw = (w & 1) * 32;
  int r0 = blockIdx.x * 64, n0 = blockIdx.y * 64;
  int z16 = blockIdx.z;
  bool isK = z16 >= 8;
  int z = z16 & 7, zb = z >> 2, zh = z & 3;
  const bf16* A = qkvb + (isK ? 256 : 0) + (long)zb * 1572864 + zh * 64;
  f32x4 zv = {0.f, 0.f, 0.f, 0.f};
  f32x4 acc[2][2] = {{zv, zv}, {zv, zv}};
  const bf16* Ag = A + (long)(r0 + (tid >> 2)) * 768 + ((tid & 3) * 8);
  const bf16* Bg = pm + (long)(n0 + (tid >> 2)) * 64 + ((tid & 3) * 8);
  llds16(Ag, &As[tid * 8]);
  llds16(Ag + 32, &As[tid * 8 + 2048]);
  llds16(Bg, &Bs[tid * 8]);
  llds16(Bg + 32, &Bs[tid * 8 + 2048]);
  __syncthreads();
#pragma unroll
  for (int c = 0; c < 2; ++c) {
    short8 a0 = *(const short8*)&As[c * 2048 + (rw + l15) * 32 + quad * 8];
    short8 a1 = *(const short8*)&As[c * 2048 + (rw + 16 + l15) * 32 + quad * 8];
    short8 b0 = *(const short8*)&Bs[c * 2048 + (cw + l15) * 32 + quad * 8];
    short8 b1 = *(const short8*)&Bs[c * 2048 + (cw + 16 + l15) * 32 + quad * 8];
    acc[0][0] = __builtin_amdgcn_mfma_f32_16x16x32_bf16(a0, b0, acc[0][0], 0, 0, 0);
    acc[0][1] = __builtin_amdgcn_mfma_f32_16x16x32_bf16(a0, b1, acc[0][1], 0, 0, 0);
    acc[1][0] = __builtin_amdgcn_mfma_f32_16x16x32_bf16(a1, b0, acc[1][0], 0, 0, 0);
    acc[1][1] = __builtin_amdgcn_mfma_f32_16x16x32_bf16(a1, b1, acc[1][1], 0, 0, 0);
  }
  bf16* qfz = qf + (long)zb * 3145728 + (long)zh * 786432;
  unsigned short* kfz = (unsigned short*)kfT + (long)zb * 3145728 + (long)zh * 786432;
  float* ksz = ksum + z * 384;
#pragma unroll
  for (int mi = 0; mi < 2; ++mi)
#pragma unroll
    for (int nj = 0; nj < 2; ++nj) {
      int colg = n0 + cw + nj * 16 + l15;
      int rbase = r0 + rw + mi * 16 + quad * 4;
      float ov[4];
#pragma unroll
      for (int r = 0; r < 4; ++r)
        ov[r] = fmaxf(acc[mi][nj][r] * dn, 0.f) + 1e-3f;
      if (!isK) {
#pragma unroll
        for (int r = 0; r < 4; ++r)
          qfz[(long)(rbase + r) * 384 + colg] = __float2bfloat16(ov[r]);
      } else {
        ushort4 p;
        p.x = f2bu(ov[0]); p.y = f2bu(ov[1]); p.z = f2bu(ov[2]); p.w = f2bu(ov[3]);
        *(ushort4*)&kfz[(long)colg * 2048 + rbase] = p;
        atomicAdd(&ksz[colg], ov[0] + ov[1] + ov[2] + ov[3]);
      }
    }
}

// ---------------------------------------------------------------------------
// MFMA bf16 GEMM: C = epi(A @ Bt^T).  A [M][K] bf16, Bt [N][K] bf16.
// 64x64 tile, 4 waves 2x2 of 32x32, K staged 64/iter via global_load_lds.
// EPI: 0 +bias  | 1 +bias+res(f32, ldc)  | 3 acc*rowsc[row]
//      5 qkv split: col<512 -> C[row*768+col]; else vT (C2), T=2048 hardcoded
//      7 split-K: atomicAdd into f32 C
//      8 GLU: B2 = Bt + sRb; C = gelu(acc+bias[c]) * (acc2+bias[c+1024]), bf16
// z batch: zb=z/Hdiv, zh=z%Hdiv offsets on A/Bt/C/rowsc.
// ---------------------------------------------------------------------------
template <typename CTy, int EPI>
__global__ __launch_bounds__(256) void mgemm_kernel(
    const bf16* __restrict__ A, const bf16* __restrict__ Bt,
    const float* __restrict__ bias, const float* __restrict__ res,
    const float* __restrict__ rowsc, CTy* __restrict__ C, bf16* __restrict__ C2,
    int K, int lda, int ldbt, int ldc,
    long sAb, long sAh, long sBb, long sBh, long sCb, long sCh,
    long sRb, long sRh, int Hdiv, float alpha)
{
  __shared__ short As[4096];
  __shared__ short Bs[4096];
  __shared__ short Bs2[(EPI == 8) ? 4096 : 8];
  int tid = threadIdx.x;
  int lane = tid & 63, w = tid >> 6;
  int quad = lane >> 4, l15 = lane & 15;
  int rw = (w >> 1) * 32, cw = (w & 1) * 32;
  int r0 = blockIdx.x * 64, n0 = blockIdx.y * 64;
  int zb = blockIdx.z / Hdiv, zh = blockIdx.z % Hdiv;
  A += zb * sAb + zh * sAh;
  Bt += zb * sBb + zh * sBh;
  C += zb * sCb + zh * sCh;
  if (res) res += zb * sCb + zh * sCh;
  const float* rsp = (EPI == 3) ? rowsc + zb * sRb + zh * sRh : nullptr;
  f32x4 zv = {0.f, 0.f, 0.f, 0.f};
  f32x4 acc[2][2] = {{zv, zv}, {zv, zv}};
  f32x4 acc2[2][2] = {{zv, zv}, {zv, zv}};
  const bf16* Ag = A + (long)(r0 + (tid >> 2)) * lda + ((tid & 3) * 8);
  const bf16* Bg = Bt + (long)(n0 + (tid >> 2)) * ldbt + ((tid & 3) * 8);
  const bf16* Bg2 = (EPI == 8) ? Bg + sRb : nullptr;
  short* Asd = &As[tid * 8];
  short* Bsd = &Bs[tid * 8];
  short* Bs2d = &Bs2[(EPI == 8) ? tid * 8 : 0];
  for (int k0 = 0; k0 < K; k0 += 64) {
    if (k0) __syncthreads();
    llds16(Ag + k0, Asd);
    llds16(Ag + k0 + 32, Asd + 2048);
    llds16(Bg + k0, Bsd);
    llds16(Bg + k0 + 32, Bsd + 2048);
    if constexpr (EPI == 8) {
      llds16(Bg2 + k0, Bs2d);
      llds16(Bg2 + k0 + 32, Bs2d + 2048);
    }
    __syncthreads();
#pragma unroll
    for (int c = 0; c < 2; ++c) {
      short8 a0 = *(const short8*)&As[c * 2048 + (rw + l15) * 32 + quad * 8];
      short8 a1 = *(const short8*)&As[c * 2048 + (rw + 16 + l15) * 32 + quad * 8];
      short8 b0 = *(const short8*)&Bs[c * 2048 + (cw + l15) * 32 + quad * 8];
      short8 b1 = *(const short8*)&Bs[c * 2048 + (cw + 16 + l15) * 32 + quad * 8];
      acc[0][0] = __builtin_amdgcn_mfma_f32_16x16x32_bf16(a0, b0, acc[0][0], 0, 0, 0);
      acc[0][1] = __builtin_amdgcn_mfma_f32_16x16x32_bf16(a0, b1, acc[0][1], 0, 0, 0);
      acc[1][0] = __builtin_amdgcn_mfma_f32_16x16x32_bf16(a1, b0, acc[1][0], 0, 0, 0);
      acc[1][1] = __builtin_amdgcn_mfma_f32_16x16x32_bf16(a1, b1, acc[1][1], 0, 0, 0);
      if constexpr (EPI == 8) {
        short8 c0 = *(const short8*)&Bs2[c * 2048 + (cw + l15) * 32 + quad * 8];
        short8 c1 = *(const short8*)&Bs2[c * 2048 + (cw + 16 + l15) * 32 + quad * 8];
        acc2[0][0] = __builtin_amdgcn_mfma_f32_16x16x32_bf16(a0, c0, acc2[0][0], 0, 0, 0);
        acc2[0][1] = __builtin_amdgcn_mfma_f32_16x16x32_bf16(a0, c1, acc2[0][1], 0, 0, 0);
        acc2[1][0] = __builtin_amdgcn_mfma_f32_16x16x32_bf16(a1, c0, acc2[1][0], 0, 0, 0);
        acc2[1][1] = __builtin_amdgcn_mfma_f32_16x16x32_bf16(a1, c1, acc2[1][1], 0, 0, 0);
      }
    }
  }
#pragma unroll
  for (int mi = 0; mi < 2; ++mi)
#pragma unroll
    for (int nj = 0; nj < 2; ++nj) {
      int colg = n0 + cw + nj * 16 + l15;
      float bv_ = bias ? bias[colg] : 0.f;
      float bv2 = (EPI == 8) ? bias[colg + 1024] : 0.f;
      int rbase = r0 + rw + mi * 16 + quad * 4;
      float ov[4];
#pragma unroll
      for (int r = 0; r < 4; ++r) {
        float v = acc[mi][nj][r];
        if constexpr (EPI == 0 || EPI == 5) {
          v += bv_;
        } else if constexpr (EPI == 1) {
          v += bv_ + res[(long)(rbase + r) * ldc + colg];
        } else if constexpr (EPI == 3) {
          v *= rsp[rbase + r];
        } else if constexpr (EPI == 8) {
          v = gelu_exact(v + bv_) * (acc2[mi][nj][r] + bv2);
        }
        ov[r] = v;
      }
      if constexpr (EPI == 5) {
        if (colg < 512) {
#pragma unroll
          for (int r = 0; r < 4; ++r) sto1(&C[(long)(rbase + r) * ldc + colg], ov[r]);
        } else {
          int bb = rbase >> 11, t0 = rbase & 2047;
          long off = (((long)bb * 4 + ((colg - 512) >> 6)) * 64 + (colg & 63)) * 2048 + t0;
          ushort4 p;
          p.x = f2bu(ov[0]); p.y = f2bu(ov[1]); p.z = f2bu(ov[2]); p.w = f2bu(ov[3]);
          *(ushort4*)((unsigned short*)C2 + off) = p;
        }
      } else if constexpr (EPI == 7) {
#pragma unroll
        for (int r = 0; r < 4; ++r)
          atomicAdd((float*)&C[(long)(rbase + r) * ldc + colg], ov[r]);
      } else {
#pragma unroll
        for (int r = 0; r < 4; ++r) sto1(&C[(long)(rbase + r) * ldc + colg], ov[r]);
      }
    }
  (void)alpha;
}

// ---------------------------------------------------------------------------
// LayerNorm: one wave per row; OTy-typed primary output.
// ---------------------------------------------------------------------------
template <int DIM, bool RELU, bool ADDPOS, bool DUAL, typename OTy>
__global__ __launch_bounds__(256) void ln_kernel(
    const float* __restrict__ in, const float* __restrict__ g,
    const float* __restrict__ b, const float* __restrict__ pos,
    OTy* __restrict__ out0, float* __restrict__ out1)
{
  constexpr int CH = DIM / 64;
  int row = blockIdx.x * 4 + (threadIdx.x >> 6);
  int lane = threadIdx.x & 63;
  const float* rp = in + (long)row * DIM + lane * CH;
  float v[CH];
#pragma unroll
  for (int i = 0; i < CH; ++i) v[i] = rp[i];
  float s = 0.f;
#pragma unroll
  for (int i = 0; i < CH; ++i) s += v[i];
#pragma unroll
  for (int o = 32; o > 0; o >>= 1) s += __shfl_xor(s, o, 64);
  float mean = s * (1.f / DIM);
  float q = 0.f;
#pragma unroll
  for (int i = 0; i < CH; ++i) { float d = v[i] - mean; q += d * d; }
#pragma unroll
  for (int o = 32; o > 0; o >>= 1) q += __shfl_xor(q, o, 64);
  float rstd = rsqrtf(q * (1.f / DIM) + 1e-5f);
  int t = row & 2047;
#pragma unroll
  for (int i = 0; i < CH; ++i) {
    int c = lane * CH + i;
    float o = (v[i] - mean) * rstd * g[c] + b[c];
    if constexpr (ADDPOS) o += pos[(long)t * DIM + c];
    if constexpr (RELU) o = fmaxf(o, 0.f);
    sto1(&out0[(long)row * DIM + c], o);
    if constexpr (DUAL) out1[(long)row * DIM + c] = o;
  }
}

__global__ __launch_bounds__(256) void dinv_kernel(
    const bf16* __restrict__ qf, const float* __restrict__ ksum,
    float* __restrict__ dinv)
{
  int z = blockIdx.x;
  int t = blockIdx.y * 4 + (threadIdx.x >> 6);
  int lane = threadIdx.x & 63;
  const bf16* qr = qf + ((long)z * 2048 + t) * 384;
  const float* ks = ksum + z * 384;
  float acc = 0.f;
#pragma unroll
  for (int i = 0; i < 6; ++i) {
    int j = lane + i * 64;
    acc = fmaf(tof(qr[j]), ks[j], acc);
  }
#pragma unroll
  for (int o = 32; o > 0; o >>= 1) acc += __shfl_xor(acc, o, 64);
  if (lane == 0) dinv[z * 2048 + t] = 1.f / acc;
}

__global__ __launch_bounds__(256) void clf2_kernel(
    const float* __restrict__ c2, const float* __restrict__ w,
    const float* __restrict__ b, float* __restrict__ out)
{
  int row = blockIdx.x * 4 + (threadIdx.x >> 6);
  int lane = threadIdx.x & 63;
  const float* rp = c2 + (long)row * 128 + lane * 2;
  float acc = rp[0] * w[lane * 2] + rp[1] * w[lane * 2 + 1];
#pragma unroll
  for (int o = 32; o > 0; o >>= 1) acc += __shfl_xor(acc, o, 64);
  if (lane == 0) out[row] = acc + b[0];
}

// ---------------------------------------------------------------------------
extern "C" void kernel_launch(void* const* d_in, const int* in_sizes, int n_in,
                              void* d_out, int out_size, void* d_ws, size_t ws_size,
                              hipStream_t stream)
{
  const float* X    = (const float*)d_in[0];
  const float* c0w  = (const float*)d_in[1];
  const float* d1w  = (const float*)d_in[2];
  const float* d1b  = (const float*)d_in[3];
  const float* p1w  = (const float*)d_in[4];
  const float* p1b  = (const float*)d_in[5];
  const float* g1   = (const float*)d_in[6];
  const float* b1   = (const float*)d_in[7];
  const float* m1   = (const float*)d_in[8];
  const float* v1   = (const float*)d_in[9];
  const float* d2w  = (const float*)d_in[10];
  const float* d2b  = (const float*)d_in[11];
  const float* p2w  = (const float*)d_in[12];
  const float* p2b  = (const float*)d_in[13];
  const float* g2   = (const float*)d_in[14];
  const float* b2   = (const float*)d_in[15];
  const float* m2   = (const float*)d_in[16];
  const float* v2   = (const float*)d_in[17];
  const float* projw= (const float*)d_in[18];
  const float* projb= (const float*)d_in[19];
  const float* ln0g = (const float*)d_in[20];
  const float* ln0b = (const float*)d_in[21];
  const float* pos  = (const float*)d_in[22];
  const float* ln1g = (const float*)d_in[23];
  const float* ln1b = (const float*)d_in[24];
  const float* wq   = (const float*)d_in[25];
  const float* bq   = (const float*)d_in[26];
  const float* wk   = (const float*)d_in[27];
  const float* bk   = (const float*)d_in[28];
  const float* wv   = (const float*)d_in[29];
  const float* bv   = (const float*)d_in[30];
  const float* wo   = (const float*)d_in[31];
  const float* bo   = (const float*)d_in[32];
  const float* pmat = (const float*)d_in[33];
  const float* ln2g = (const float*)d_in[34];
  const float* ln2b = (const float*)d_in[35];
  const float* ffw1 = (const float*)d_in[36];
  const float* ffb1 = (const float*)d_in[37];
  const float* ffw2 = (const float*)d_in[38];
  const float* ffb2 = (const float*)d_in[39];
  const float* cw1  = (const float*)d_in[40];
  const float* cb1  = (const float*)d_in[41];
  const float* clng = (const float*)d_in[42];
  const float* clnb = (const float*)d_in[43];
  const float* cw2  = (const float*)d_in[44];
  const float* cb2  = (const float*)d_in[45];
  (void)in_sizes; (void)n_in; (void)out_size; (void)ws_size;

  // ---- workspace (float-slot offsets); total 22,662,144 fl = 90.6 MB ----
  float* ws     = (float*)d_ws;
  float* x1     = ws;                          // 1,048,576
  float* x2     = ws + 1048576;
  float* lnb32  = ws + 2097152;
  bf16*  lnb16  = (bf16*)(ws + 3145728);       // [4096][256]
  bf16*  hconvb = (bf16*)(ws + 3407872);       // [4096][256]
  // --- transformer scratch inside A1 span [3670016, 20447232) ---
  bf16*  obufb  = (bf16*)(ws + 3670016);       // [4096][256]
  bf16*  qkvb   = (bf16*)(ws + 3932160);       // [4096][768] (cols 512+ unused)
  bf16*  vT     = (bf16*)(ws + 5505024);       // [8][64][2048]
  bf16*  qf     = (bf16*)(ws + 6029312);       // [8][2048][384]
  bf16*  kfT    = (bf16*)(ws + 9175040);       // [8][384][2048]
  float* ctx32  = ws + 12320768;               // [8][64][384] fp32 (196608)
  float* ksum   = ws + 12517376;               // 4096 (contiguous after ctx32)
  float* dinvp  = ws + 12521472;               // 16384
  bf16*  ctxb   = (bf16*)(ws + 12537856);      // [8][64][384] bf16 (49152 fl)
  float* c1     = ws + 12587008;               // classifier [4096][128]
  float* c2     = ws + 13111296;               // [4096][128] -> 13635584
  bf16*  gb2    = (bf16*)(ws + 16633856);      // [4096][1024]
  bf16*  A1     = (bf16*)(ws + 3670016);       // conv-only, 16,777,216 fl span
  // --- converted weights (survive A1; after its span) ---
  bf16*  wqkv_bf= (bf16*)(ws + 20447232);      // [4][768][256]
  float* qkvbias= ws + 20840448;               // [4][768]
  bf16*  f1w_bf = (bf16*)(ws + 20843520);      // [4][2048][256]
  bf16*  f2w_bf = (bf16*)(ws + 21892096);      // [4][256][1024]
  bf16*  wo_bf  = (bf16*)(ws + 22416384);      // [4][256][256]
  bf16*  pm_bf  = (bf16*)(ws + 22547456);      // [4][384][64]
  bf16*  projwT = (bf16*)(ws + 22596608);      // [256][256]
  bf16*  cw1T   = (bf16*)(ws + 22629376);      // [128][256]
  bf16*  pw2_bf = (bf16*)(ws + 22645760);      // [256][128] -> end 22662144
  bf16*  sbuf   = qkvb;                        // classifier reuse

  const float dn = 0.35355339059327378f;  // 64^-0.25

  // --- weight conversion ---
  pack_qkv_kernel<<<3072, 256, 0, stream>>>(wq, wk, wv, wqkv_bf);
  pack_qkvbias_kernel<<<12, 256, 0, stream>>>(bq, bk, bv, qkvbias);
  tconv_kernel<<<dim3(2048, 1, 4), 256, 0, stream>>>(ffw1, f1w_bf, 256, 2048, 524288, 524288);
  tconv_kernel<<<dim3(1024, 1, 4), 256, 0, stream>>>(ffw2, f2w_bf, 1024, 256, 262144, 262144);
  tconv_kernel<<<dim3(256, 1, 4), 256, 0, stream>>>(wo, wo_bf, 256, 256, 65536, 65536);
  tconv_kernel<<<dim3(256, 1, 1), 256, 0, stream>>>(projw, projwT, 256, 256, 65536, 65536);
  tconv_kernel<<<dim3(128, 1, 1), 256, 0, stream>>>(cw1, cw1T, 256, 128, 32768, 32768);
  f2b_kernel<<<384, 256, 0, stream>>>(pmat, pm_bf, 98304);
  f2b_kernel<<<128, 256, 0, stream>>>(p2w, pw2_bf, 32768);

  // --- conv frontend ---
  front1_kernel<<<4096, 256, 0, stream>>>(X, c0w, d1w, d1b, p1w, p1b, g1, b1, m1, v1, A1);
  convtail_kernel<<<4096, 256, 0, stream>>>(A1, d2w, d2b, pw2_bf, p2b, g2, b2, m2, v2, hconvb);

  // proj + ln0 + pos -> x1 = x2
  mgemm_kernel<float, 0><<<dim3(64, 4, 1), 256, 0, stream>>>(
      hconvb, projwT, projb, nullptr, nullptr, lnb32, nullptr,
      256, 256, 256, 256, 0, 0, 0, 0, 0, 0, 0, 0, 1, 1.f);
  ln_kernel<256, false, true, true, float><<<1024, 256, 0, stream>>>(
      lnb32, ln0g, ln0b, pos, x1, x2);

  for (int l = 0; l < 4; ++l) {
    const bf16* wqkv_l = wqkv_bf + (size_t)l * 196608;
    const float* qb_l  = qkvbias + l * 768;
    const bf16* pm_l   = pm_bf + (size_t)l * 24576;
    const bf16* wo_l   = wo_bf + (size_t)l * 65536;
    const float* bov   = bo + l * 256;
    const bf16* f1w_l  = f1w_bf + (size_t)l * 524288;
    const float* f1b_l = ffb1 + l * 2048;
    const bf16* f2w_l  = f2w_bf + (size_t)l * 262144;
    const float* f2b_l = ffb2 + l * 256;

    // a = LN(x2) -> bf16
    ln_kernel<256, false, false, false, bf16><<<1024, 256, 0, stream>>>(
        x2, ln1g + l * 256, ln1b + l * 256, nullptr, lnb16, nullptr);
    // qkv: q,k -> qkvb rows; v -> vT transposed
    mgemm_kernel<bf16, 5><<<dim3(64, 12, 1), 256, 0, stream>>>(
        lnb16, wqkv_l, qb_l, nullptr, nullptr, qkvb, vT,
        256, 256, 256, 768, 0, 0, 0, 0, 0, 0, 0, 0, 1, 1.f);
    // zero ctx32 + ksum (contiguous, 200704 floats)
    zero4_kernel<<<196, 256, 0, stream>>>(ctx32);
    // fused FAVOR: qf (row) + kfT (transposed, ksum atomics)
    favor_kernel<<<dim3(32, 6, 16), 256, 0, stream>>>(
        qkvb, pm_l, qf, kfT, ksum, dn);
    // dinv
    dinv_kernel<<<dim3(8, 512), 256, 0, stream>>>(qf, ksum, dinvp);
    // ctx split-K: 8 segments of 256 over t;  ctx32[z][d][j] += partials
    mgemm_kernel<float, 7><<<dim3(1, 6, 64), 256, 0, stream>>>(
        vT, kfT, nullptr, nullptr, nullptr, ctx32, nullptr,
        256, 2048, 2048, 384, 131072, 256, 786432, 256, 24576, 0, 0, 0, 8, 1.f);
    f2b_kernel<<<768, 256, 0, stream>>>(ctx32, ctxb, 196608);
    // o = (qf @ ctxb^T) * dinv -> obufb [b][t][h*64+d] bf16
    mgemm_kernel<bf16, 3><<<dim3(32, 1, 8), 256, 0, stream>>>(
        qf, ctxb, nullptr, nullptr, dinvp, obufb, nullptr,
        384, 384, 384, 256, 3145728, 786432, 98304, 24576, 524288, 64, 8192, 2048, 4, 1.f);
    // x1 += o @ wo + bo
    mgemm_kernel<float, 1><<<dim3(64, 4, 1), 256, 0, stream>>>(
        obufb, wo_l, bov, x1, nullptr, x1, nullptr,
        256, 256, 256, 256, 0, 0, 0, 0, 0, 0, 0, 0, 1, 1.f);
    // f = LN(x1) -> bf16
    ln_kernel<256, false, false, false, bf16><<<1024, 256, 0, stream>>>(
        x1, ln2g + l * 256, ln2b + l * 256, nullptr, lnb16, nullptr);
    // gb2 = gelu(f@W1a + b1a) * (f@W1b + b1b)   (fused GLU; B2 via sRb)
    mgemm_kernel<bf16, 8><<<dim3(64, 16, 1), 256, 0, stream>>>(
        lnb16, f1w_l, f1b_l, nullptr, nullptr, gb2, nullptr,
        256, 256, 256, 1024, 0, 0, 0, 0, 0, 0, 262144, 0, 1, 1.f);
    // x2 += gb2 @ ffw2 + b
    mgemm_kernel<float, 1><<<dim3(64, 4, 1), 256, 0, stream>>>(
        gb2, f2w_l, f2b_l, x2, nullptr, x2, nullptr,
        1024, 1024, 1024, 256, 0, 0, 0, 0, 0, 0, 0, 0, 1, 1.f);
  }

  // classifier
  sumb_kernel<<<1024, 256, 0, stream>>>(x1, x2, sbuf);
  mgemm_kernel<float, 0><<<dim3(64, 2, 1), 256, 0, stream>>>(
      sbuf, cw1T, cb1, nullptr, nullptr, c1, nullptr,
      256, 256, 256, 128, 0, 0, 0, 0, 0, 0, 0, 0, 1, 1.f);
  ln_kernel<128, true, false, false, float><<<1024, 256, 0, stream>>>(
      c1, clng, clnb, nullptr, c2, nullptr);
  clf2_kernel<<<1024, 256, 0, stream>>>(c2, cw2, cb2, (float*)d_out);
}

// Round 10
// 640.462 us; speedup vs baseline: 1.4484x; 1.4484x over previous
//
#include <hip/hip_runtime.h>
#include <hip/hip_bf16.h>
#include <math.h>

using bf16 = __hip_bfloat16;
typedef __attribute__((ext_vector_type(8))) short short8;
typedef __attribute__((ext_vector_type(4))) float f32x4;

__device__ __forceinline__ float tof(float x) { return x; }
__device__ __forceinline__ float tof(bf16 x) { return __bfloat162float(x); }
__device__ __forceinline__ float b2f(unsigned short u) {
  union { float f; unsigned int i; } c; c.i = ((unsigned int)u) << 16; return c.f;
}
__device__ __forceinline__ unsigned short f2bu(float v) {
  bf16 h = __float2bfloat16(v);
  return *(unsigned short*)&h;
}
__device__ __forceinline__ void sto1(float* p, float v) { *p = v; }
__device__ __forceinline__ void sto1(bf16* p, float v) { *p = __float2bfloat16(v); }

__device__ __forceinline__ float gelu_exact(float x) {
  return 0.5f * x * (1.f + erff(x * 0.70710678118654752f));
}

// async global->LDS, 16B/lane; LDS dest = wave base + lane*16 (m97 pattern).
__device__ __forceinline__ void llds16(const bf16* g, short* l) {
  __builtin_amdgcn_global_load_lds((const __attribute__((address_space(1))) void*)g,
                                   (__attribute__((address_space(3))) void*)l, 16, 0, 0);
}

// ---------------------------------------------------------------------------
// Weight conversion (once per launch; small).
// ---------------------------------------------------------------------------
__global__ __launch_bounds__(256) void pack_qkv_kernel(
    const float* __restrict__ wq, const float* __restrict__ wk,
    const float* __restrict__ wv, bf16* __restrict__ out)
{
  int idx = blockIdx.x * 256 + threadIdx.x;   // < 4*768*256
  int k = idx & 255;
  int nl = idx >> 8;
  int n = nl % 768, l = nl / 768;
  const float* src = (n < 256) ? wq : (n < 512 ? wk : wv);
  out[idx] = __float2bfloat16(src[(long)l * 65536 + k * 256 + (n & 255)]);
}

__global__ __launch_bounds__(256) void pack_qkvbias_kernel(
    const float* __restrict__ bq, const float* __restrict__ bk,
    const float* __restrict__ bv, float* __restrict__ out)
{
  int i = blockIdx.x * 256 + threadIdx.x;   // < 3072
  if (i >= 3072) return;
  int n = i % 768, l = i / 768;
  const float* src = (n < 256) ? bq : (n < 512 ? bk : bv);
  out[i] = src[l * 256 + (n & 255)];
}

// out[l][n][k] = in[l][k][n], bf16
__global__ __launch_bounds__(256) void tconv_kernel(
    const float* __restrict__ in, bf16* __restrict__ out,
    int K, int N, long sin, long sout)
{
  int l = blockIdx.z;
  int idx = blockIdx.x * 256 + threadIdx.x;
  int k = idx % K, n = idx / K;
  out[l * sout + idx] = __float2bfloat16(in[l * sin + (long)k * N + n]);
}

__global__ __launch_bounds__(256) void f2b_kernel(
    const float* __restrict__ in, bf16* __restrict__ out, int n)
{
  int i = blockIdx.x * 256 + threadIdx.x;
  if (i < n) out[i] = __float2bfloat16(in[i]);
}

__global__ __launch_bounds__(256) void zero4_kernel(float* __restrict__ p) {
  int i = (blockIdx.x * 256 + threadIdx.x) * 4;
  float4 z; z.x = 0.f; z.y = 0.f; z.z = 0.f; z.w = 0.f;
  *(float4*)&p[i] = z;
}

// s = x1 + x2, bf16 (classifier input)
__global__ __launch_bounds__(256) void sumb_kernel(
    const float* __restrict__ a, const float* __restrict__ b, bf16* __restrict__ o)
{
  int i = (blockIdx.x * 256 + threadIdx.x) * 4;
  float4 x = *(const float4*)&a[i];
  float4 y = *(const float4*)&b[i];
  ushort4 p;
  p.x = f2bu(x.x + y.x); p.y = f2bu(x.y + y.y);
  p.z = f2bu(x.z + y.z); p.w = f2bu(x.w + y.w);
  *(ushort4*)((unsigned short*)o + i) = p;
}

// ---------------------------------------------------------------------------
// Conv frontend stage 1: conv0+dw1+pw1+bn1+relu -> A1[b][t][f][ci] bf16
// ---------------------------------------------------------------------------
__global__ __launch_bounds__(256) void front1_kernel(
    const float* __restrict__ x, const float* __restrict__ c0w,
    const float* __restrict__ d1w, const float* __restrict__ d1b,
    const float* __restrict__ p1w, const float* __restrict__ p1b,
    const float* __restrict__ g1, const float* __restrict__ b1,
    const float* __restrict__ m1, const float* __restrict__ v1,
    bf16* __restrict__ A1)
{
  __shared__ float sd[256];
  __shared__ float spw[512];
  __shared__ float ss[128], st[128], sb[128];
  int tid = threadIdx.x;
  int bt = blockIdx.x;
  int b = bt >> 11, t = bt & 2047;
  if (tid < 128) {
    float s = g1[tid] * rsqrtf(v1[tid] + 1e-5f);
    ss[tid] = s;
    st[tid] = b1[tid] - m1[tid] * s;
    sb[tid] = p1b[tid];
#pragma unroll
    for (int c = 0; c < 4; ++c) spw[c * 128 + tid] = p1w[tid * 4 + c];
  }
  {
    int c = tid >> 6, f = tid & 63;
    float cw = c0w[c];
    float acc = d1b[c];
#pragma unroll
    for (int kh = 0; kh < 3; ++kh) {
      int fi = f + kh - 1;
      if (fi < 0 || fi >= 64) continue;
#pragma unroll
      for (int kw = 0; kw < 3; ++kw) {
        int ti = t + kw - 1;
        if (ti < 0 || ti >= 2048) continue;
        acc += d1w[c * 9 + kh * 3 + kw] * cw * x[((long)b * 2048 + ti) * 64 + fi];
      }
    }
    sd[c * 64 + f] = acc;
  }
  __syncthreads();
  long ob = (long)bt * 8192;
  for (int it = 0; it < 32; ++it) {
    int o = it * 256 + tid;
    int f = o >> 7, ci = o & 127;
    float pre = sb[ci];
#pragma unroll
    for (int c = 0; c < 4; ++c) pre = fmaf(spw[c * 128 + ci], sd[c * 64 + f], pre);
    A1[ob + o] = __float2bfloat16(fmaxf(fmaf(ss[ci], pre, st[ci]), 0.f));
  }
}

// ---------------------------------------------------------------------------
// Conv tail: dw2 (VALU, ci8 per thread, 16B taps) + pw2 (MFMA) + bn2 + relu +
// mean(f) -> hconvb bf16.  One block per (b,t).  LDS 39.4 KB -> 4 blocks/CU.
// ---------------------------------------------------------------------------
__global__ __launch_bounds__(256, 4) void convtail_kernel(
    const bf16* __restrict__ A1, const float* __restrict__ w,
    const float* __restrict__ wb, const bf16* __restrict__ w2b,
    const float* __restrict__ pb, const float* __restrict__ g2,
    const float* __restrict__ b2, const float* __restrict__ m2,
    const float* __restrict__ v2, bf16* __restrict__ hconvb)
{
  __shared__ short dw2s[64 * 136];
  __shared__ short Bs[64 * 136];
  __shared__ float red[1024];
  __shared__ float ssc[64], ssh[64];
  int tid = threadIdx.x;
  int lane = tid & 63, wv = tid >> 6;
  int quad = lane >> 4, l15 = lane & 15;
  int rw = (wv >> 1) * 32, cw = (wv & 1) * 32;
  int bt = blockIdx.x, b = bt >> 11, t = bt & 2047;
  int ci8 = (tid & 15) * 8;
  // per-thread dw2 weights / bias in registers (ci8 invariant across passes)
  float wreg[9][8], breg[8];
#pragma unroll
  for (int c = 0; c < 8; ++c) {
    breg[c] = wb[ci8 + c];
#pragma unroll
    for (int kk = 0; kk < 9; ++kk) wreg[kk][c] = w[(ci8 + c) * 9 + kk];
  }
  const unsigned short* A1u = (const unsigned short*)A1;
  for (int pass = 0; pass < 4; ++pass) {
    int f = pass * 16 + (tid >> 4);
    float a[8];
#pragma unroll
    for (int c = 0; c < 8; ++c) a[c] = breg[c];
#pragma unroll
    for (int kh = 0; kh < 3; ++kh) {
      int fi = f + kh - 1;
      if (fi < 0 || fi >= 64) continue;
#pragma unroll
      for (int kw = 0; kw < 3; ++kw) {
        int ti = t + kw - 1;
        if (ti < 0 || ti >= 2048) continue;
        short8 u = *(const short8*)&A1u[(((long)b * 2048 + ti) * 64 + fi) * 128 + ci8];
        int kk = kh * 3 + kw;
#pragma unroll
        for (int c = 0; c < 8; ++c)
          a[c] = fmaf(wreg[kk][c], b2f((unsigned short)u[c]), a[c]);
      }
    }
    short8 p;
#pragma unroll
    for (int c = 0; c < 8; ++c) p[c] = (short)f2bu(a[c]);
    *(short8*)&dw2s[f * 136 + ci8] = p;
  }
  for (int ct = 0; ct < 4; ++ct) {
    int co0 = ct * 64;
    __syncthreads();   // dw2s ready (ct=0) / red consumed (ct>0)
    for (int l2 = 0; l2 < 4; ++l2) {
      int idx = l2 * 256 + tid;
      int row = idx >> 4, koff = (idx & 15) * 8;
      *(short8*)&Bs[row * 136 + koff] =
          *(const short8*)&w2b[(long)(co0 + row) * 128 + koff];
    }
    if (tid < 64) {
      int co = co0 + tid;
      float s = g2[co] * rsqrtf(v2[co] + 1e-5f);
      ssc[tid] = s;
      ssh[tid] = b2[co] - m2[co] * s + s * pb[co];
    }
    __syncthreads();
    f32x4 zv = {0.f, 0.f, 0.f, 0.f};
    f32x4 acc[2][2] = {{zv, zv}, {zv, zv}};
#pragma unroll
    for (int kc = 0; kc < 4; ++kc) {
      short8 a0 = *(const short8*)&dw2s[(rw + l15) * 136 + kc * 32 + quad * 8];
      short8 a1 = *(const short8*)&dw2s[(rw + 16 + l15) * 136 + kc * 32 + quad * 8];
      short8 b0 = *(const short8*)&Bs[(cw + l15) * 136 + kc * 32 + quad * 8];
      short8 b1 = *(const short8*)&Bs[(cw + 16 + l15) * 136 + kc * 32 + quad * 8];
      acc[0][0] = __builtin_amdgcn_mfma_f32_16x16x32_bf16(a0, b0, acc[0][0], 0, 0, 0);
      acc[0][1] = __builtin_amdgcn_mfma_f32_16x16x32_bf16(a0, b1, acc[0][1], 0, 0, 0);
      acc[1][0] = __builtin_amdgcn_mfma_f32_16x16x32_bf16(a1, b0, acc[1][0], 0, 0, 0);
      acc[1][1] = __builtin_amdgcn_mfma_f32_16x16x32_bf16(a1, b1, acc[1][1], 0, 0, 0);
    }
#pragma unroll
    for (int mi = 0; mi < 2; ++mi)
#pragma unroll
      for (int nj = 0; nj < 2; ++nj) {
        int colg = cw + nj * 16 + l15;
        float s = ssc[colg], sh = ssh[colg];
        float sum = 0.f;
#pragma unroll
        for (int r = 0; r < 4; ++r) sum += fmaxf(fmaf(s, acc[mi][nj][r], sh), 0.f);
        int rowgroup = (wv >> 1) * 8 + mi * 4 + quad;
        red[rowgroup * 64 + colg] = sum;
      }
    __syncthreads();
    if (tid < 64) {
      float s = 0.f;
#pragma unroll
      for (int r = 0; r < 16; ++r) s += red[r * 64 + tid];
      hconvb[(long)bt * 256 + co0 + tid] = __float2bfloat16(s * (1.f / 64.f));
    }
  }
}

// ---------------------------------------------------------------------------
// FAVOR feature kernel (fused qf + kfT): F = relu(dn * X @ pm^T) + 1e-3.
// grid (32, 6, 16): z<8 -> q head z, row-layout qf[z][t][j];
//                   z>=8 -> k head z-8, transposed kfT[z][j][t].
// kfT strides are bf16 ELEMENTS (r5-r7 byte-stride bug documented in journal).
// ksum computed separately by rowsum_kernel — per-element global atomics here
// cost ~250us/launch (r9 regression: ~512 serialized atomics per address).
// ---------------------------------------------------------------------------
__global__ __launch_bounds__(256) void favor_kernel(
    const bf16* __restrict__ qkvb, const bf16* __restrict__ pm,
    bf16* __restrict__ qf, bf16* __restrict__ kfT, float dn)
{
  __shared__ short As[4096];
  __shared__ short Bs[4096];
  int tid = threadIdx.x;
  int lane = tid & 63, w = tid >> 6;
  int quad = lane >> 4, l15 = lane & 15;
  int rw = (w >> 1) * 32, cw = (w & 1) * 32;
  int r0 = blockIdx.x * 64, n0 = blockIdx.y * 64;
  int z16 = blockIdx.z;
  bool isK = z16 >= 8;
  int z = z16 & 7, zb = z >> 2, zh = z & 3;
  const bf16* A = qkvb + (isK ? 256 : 0) + (long)zb * 1572864 + zh * 64;
  f32x4 zv = {0.f, 0.f, 0.f, 0.f};
  f32x4 acc[2][2] = {{zv, zv}, {zv, zv}};
  const bf16* Ag = A + (long)(r0 + (tid >> 2)) * 768 + ((tid & 3) * 8);
  const bf16* Bg = pm + (long)(n0 + (tid >> 2)) * 64 + ((tid & 3) * 8);
  llds16(Ag, &As[tid * 8]);
  llds16(Ag + 32, &As[tid * 8 + 2048]);
  llds16(Bg, &Bs[tid * 8]);
  llds16(Bg + 32, &Bs[tid * 8 + 2048]);
  __syncthreads();
#pragma unroll
  for (int c = 0; c < 2; ++c) {
    short8 a0 = *(const short8*)&As[c * 2048 + (rw + l15) * 32 + quad * 8];
    short8 a1 = *(const short8*)&As[c * 2048 + (rw + 16 + l15) * 32 + quad * 8];
    short8 b0 = *(const short8*)&Bs[c * 2048 + (cw + l15) * 32 + quad * 8];
    short8 b1 = *(const short8*)&Bs[c * 2048 + (cw + 16 + l15) * 32 + quad * 8];
    acc[0][0] = __builtin_amdgcn_mfma_f32_16x16x32_bf16(a0, b0, acc[0][0], 0, 0, 0);
    acc[0][1] = __builtin_amdgcn_mfma_f32_16x16x32_bf16(a0, b1, acc[0][1], 0, 0, 0);
    acc[1][0] = __builtin_amdgcn_mfma_f32_16x16x32_bf16(a1, b0, acc[1][0], 0, 0, 0);
    acc[1][1] = __builtin_amdgcn_mfma_f32_16x16x32_bf16(a1, b1, acc[1][1], 0, 0, 0);
  }
  bf16* qfz = qf + (long)zb * 3145728 + (long)zh * 786432;
  unsigned short* kfz = (unsigned short*)kfT + (long)zb * 3145728 + (long)zh * 786432;
#pragma unroll
  for (int mi = 0; mi < 2; ++mi)
#pragma unroll
    for (int nj = 0; nj < 2; ++nj) {
      int colg = n0 + cw + nj * 16 + l15;
      int rbase = r0 + rw + mi * 16 + quad * 4;
      float ov[4];
#pragma unroll
      for (int r = 0; r < 4; ++r)
        ov[r] = fmaxf(acc[mi][nj][r] * dn, 0.f) + 1e-3f;
      if (!isK) {
#pragma unroll
        for (int r = 0; r < 4; ++r)
          qfz[(long)(rbase + r) * 384 + colg] = __float2bfloat16(ov[r]);
      } else {
        ushort4 p;
        p.x = f2bu(ov[0]); p.y = f2bu(ov[1]); p.z = f2bu(ov[2]); p.w = f2bu(ov[3]);
        *(ushort4*)&kfz[(long)colg * 2048 + rbase] = p;
      }
    }
}

// ksum[z][j] = sum_t kfT[z][j][t]  (contiguous rows, no atomics)
__global__ __launch_bounds__(256) void rowsum_kernel(
    const bf16* __restrict__ kfT, float* __restrict__ ksum)
{
  int z = blockIdx.x;
  int j = blockIdx.y * 4 + (threadIdx.x >> 6);
  int lane = threadIdx.x & 63;
  const short* base = (const short*)kfT + ((long)z * 384 + j) * 2048;
  float acc = 0.f;
#pragma unroll
  for (int i = 0; i < 4; ++i) {
    short8 v = *(const short8*)&base[i * 512 + lane * 8];
#pragma unroll
    for (int e = 0; e < 8; ++e) acc += b2f((unsigned short)v[e]);
  }
#pragma unroll
  for (int o = 32; o > 0; o >>= 1) acc += __shfl_xor(acc, o, 64);
  if (lane == 0) ksum[z * 384 + j] = acc;
}

// ---------------------------------------------------------------------------
// MFMA bf16 GEMM: C = epi(A @ Bt^T).  A [M][K] bf16, Bt [N][K] bf16.
// 64x64 tile, 4 waves 2x2 of 32x32, K staged 64/iter via global_load_lds.
// EPI: 0 +bias  | 1 +bias+res(f32, ldc)  | 3 acc*rowsc[row]
//      5 qkv split: col<512 -> C[row*768+col]; else vT (C2), T=2048 hardcoded
//      7 split-K: atomicAdd into f32 C
//      8 GLU: B2 = Bt + sRb; C = gelu(acc+bias[c]) * (acc2+bias[c+1024]), bf16
// z batch: zb=z/Hdiv, zh=z%Hdiv offsets on A/Bt/C/rowsc.
// ---------------------------------------------------------------------------
template <typename CTy, int EPI>
__global__ __launch_bounds__(256) void mgemm_kernel(
    const bf16* __restrict__ A, const bf16* __restrict__ Bt,
    const float* __restrict__ bias, const float* __restrict__ res,
    const float* __restrict__ rowsc, CTy* __restrict__ C, bf16* __restrict__ C2,
    int K, int lda, int ldbt, int ldc,
    long sAb, long sAh, long sBb, long sBh, long sCb, long sCh,
    long sRb, long sRh, int Hdiv, float alpha)
{
  __shared__ short As[4096];
  __shared__ short Bs[4096];
  __shared__ short Bs2[(EPI == 8) ? 4096 : 8];
  int tid = threadIdx.x;
  int lane = tid & 63, w = tid >> 6;
  int quad = lane >> 4, l15 = lane & 15;
  int rw = (w >> 1) * 32, cw = (w & 1) * 32;
  int r0 = blockIdx.x * 64, n0 = blockIdx.y * 64;
  int zb = blockIdx.z / Hdiv, zh = blockIdx.z % Hdiv;
  A += zb * sAb + zh * sAh;
  Bt += zb * sBb + zh * sBh;
  C += zb * sCb + zh * sCh;
  if (res) res += zb * sCb + zh * sCh;
  const float* rsp = (EPI == 3) ? rowsc + zb * sRb + zh * sRh : nullptr;
  f32x4 zv = {0.f, 0.f, 0.f, 0.f};
  f32x4 acc[2][2] = {{zv, zv}, {zv, zv}};
  f32x4 acc2[2][2] = {{zv, zv}, {zv, zv}};
  const bf16* Ag = A + (long)(r0 + (tid >> 2)) * lda + ((tid & 3) * 8);
  const bf16* Bg = Bt + (long)(n0 + (tid >> 2)) * ldbt + ((tid & 3) * 8);
  const bf16* Bg2 = (EPI == 8) ? Bg + sRb : nullptr;
  short* Asd = &As[tid * 8];
  short* Bsd = &Bs[tid * 8];
  short* Bs2d = &Bs2[(EPI == 8) ? tid * 8 : 0];
  for (int k0 = 0; k0 < K; k0 += 64) {
    if (k0) __syncthreads();
    llds16(Ag + k0, Asd);
    llds16(Ag + k0 + 32, Asd + 2048);
    llds16(Bg + k0, Bsd);
    llds16(Bg + k0 + 32, Bsd + 2048);
    if constexpr (EPI == 8) {
      llds16(Bg2 + k0, Bs2d);
      llds16(Bg2 + k0 + 32, Bs2d + 2048);
    }
    __syncthreads();
#pragma unroll
    for (int c = 0; c < 2; ++c) {
      short8 a0 = *(const short8*)&As[c * 2048 + (rw + l15) * 32 + quad * 8];
      short8 a1 = *(const short8*)&As[c * 2048 + (rw + 16 + l15) * 32 + quad * 8];
      short8 b0 = *(const short8*)&Bs[c * 2048 + (cw + l15) * 32 + quad * 8];
      short8 b1 = *(const short8*)&Bs[c * 2048 + (cw + 16 + l15) * 32 + quad * 8];
      acc[0][0] = __builtin_amdgcn_mfma_f32_16x16x32_bf16(a0, b0, acc[0][0], 0, 0, 0);
      acc[0][1] = __builtin_amdgcn_mfma_f32_16x16x32_bf16(a0, b1, acc[0][1], 0, 0, 0);
      acc[1][0] = __builtin_amdgcn_mfma_f32_16x16x32_bf16(a1, b0, acc[1][0], 0, 0, 0);
      acc[1][1] = __builtin_amdgcn_mfma_f32_16x16x32_bf16(a1, b1, acc[1][1], 0, 0, 0);
      if constexpr (EPI == 8) {
        short8 c0 = *(const short8*)&Bs2[c * 2048 + (cw + l15) * 32 + quad * 8];
        short8 c1 = *(const short8*)&Bs2[c * 2048 + (cw + 16 + l15) * 32 + quad * 8];
        acc2[0][0] = __builtin_amdgcn_mfma_f32_16x16x32_bf16(a0, c0, acc2[0][0], 0, 0, 0);
        acc2[0][1] = __builtin_amdgcn_mfma_f32_16x16x32_bf16(a0, c1, acc2[0][1], 0, 0, 0);
        acc2[1][0] = __builtin_amdgcn_mfma_f32_16x16x32_bf16(a1, c0, acc2[1][0], 0, 0, 0);
        acc2[1][1] = __builtin_amdgcn_mfma_f32_16x16x32_bf16(a1, c1, acc2[1][1], 0, 0, 0);
      }
    }
  }
#pragma unroll
  for (int mi = 0; mi < 2; ++mi)
#pragma unroll
    for (int nj = 0; nj < 2; ++nj) {
      int colg = n0 + cw + nj * 16 + l15;
      float bv_ = bias ? bias[colg] : 0.f;
      float bv2 = (EPI == 8) ? bias[colg + 1024] : 0.f;
      int rbase = r0 + rw + mi * 16 + quad * 4;
      float ov[4];
#pragma unroll
      for (int r = 0; r < 4; ++r) {
        float v = acc[mi][nj][r];
        if constexpr (EPI == 0 || EPI == 5) {
          v += bv_;
        } else if constexpr (EPI == 1) {
          v += bv_ + res[(long)(rbase + r) * ldc + colg];
        } else if constexpr (EPI == 3) {
          v *= rsp[rbase + r];
        } else if constexpr (EPI == 8) {
          v = gelu_exact(v + bv_) * (acc2[mi][nj][r] + bv2);
        }
        ov[r] = v;
      }
      if constexpr (EPI == 5) {
        if (colg < 512) {
#pragma unroll
          for (int r = 0; r < 4; ++r) sto1(&C[(long)(rbase + r) * ldc + colg], ov[r]);
        } else {
          int bb = rbase >> 11, t0 = rbase & 2047;
          long off = (((long)bb * 4 + ((colg - 512) >> 6)) * 64 + (colg & 63)) * 2048 + t0;
          ushort4 p;
          p.x = f2bu(ov[0]); p.y = f2bu(ov[1]); p.z = f2bu(ov[2]); p.w = f2bu(ov[3]);
          *(ushort4*)((unsigned short*)C2 + off) = p;
        }
      } else if constexpr (EPI == 7) {
#pragma unroll
        for (int r = 0; r < 4; ++r)
          atomicAdd((float*)&C[(long)(rbase + r) * ldc + colg], ov[r]);
      } else {
#pragma unroll
        for (int r = 0; r < 4; ++r) sto1(&C[(long)(rbase + r) * ldc + colg], ov[r]);
      }
    }
  (void)alpha;
}

// ---------------------------------------------------------------------------
// LayerNorm: one wave per row; OTy-typed primary output.
// ---------------------------------------------------------------------------
template <int DIM, bool RELU, bool ADDPOS, bool DUAL, typename OTy>
__global__ __launch_bounds__(256) void ln_kernel(
    const float* __restrict__ in, const float* __restrict__ g,
    const float* __restrict__ b, const float* __restrict__ pos,
    OTy* __restrict__ out0, float* __restrict__ out1)
{
  constexpr int CH = DIM / 64;
  int row = blockIdx.x * 4 + (threadIdx.x >> 6);
  int lane = threadIdx.x & 63;
  const float* rp = in + (long)row * DIM + lane * CH;
  float v[CH];
#pragma unroll
  for (int i = 0; i < CH; ++i) v[i] = rp[i];
  float s = 0.f;
#pragma unroll
  for (int i = 0; i < CH; ++i) s += v[i];
#pragma unroll
  for (int o = 32; o > 0; o >>= 1) s += __shfl_xor(s, o, 64);
  float mean = s * (1.f / DIM);
  float q = 0.f;
#pragma unroll
  for (int i = 0; i < CH; ++i) { float d = v[i] - mean; q += d * d; }
#pragma unroll
  for (int o = 32; o > 0; o >>= 1) q += __shfl_xor(q, o, 64);
  float rstd = rsqrtf(q * (1.f / DIM) + 1e-5f);
  int t = row & 2047;
#pragma unroll
  for (int i = 0; i < CH; ++i) {
    int c = lane * CH + i;
    float o = (v[i] - mean) * rstd * g[c] + b[c];
    if constexpr (ADDPOS) o += pos[(long)t * DIM + c];
    if constexpr (RELU) o = fmaxf(o, 0.f);
    sto1(&out0[(long)row * DIM + c], o);
    if constexpr (DUAL) out1[(long)row * DIM + c] = o;
  }
}

__global__ __launch_bounds__(256) void dinv_kernel(
    const bf16* __restrict__ qf, const float* __restrict__ ksum,
    float* __restrict__ dinv)
{
  int z = blockIdx.x;
  int t = blockIdx.y * 4 + (threadIdx.x >> 6);
  int lane = threadIdx.x & 63;
  const bf16* qr = qf + ((long)z * 2048 + t) * 384;
  const float* ks = ksum + z * 384;
  float acc = 0.f;
#pragma unroll
  for (int i = 0; i < 6; ++i) {
    int j = lane + i * 64;
    acc = fmaf(tof(qr[j]), ks[j], acc);
  }
#pragma unroll
  for (int o = 32; o > 0; o >>= 1) acc += __shfl_xor(acc, o, 64);
  if (lane == 0) dinv[z * 2048 + t] = 1.f / acc;
}

__global__ __launch_bounds__(256) void clf2_kernel(
    const float* __restrict__ c2, const float* __restrict__ w,
    const float* __restrict__ b, float* __restrict__ out)
{
  int row = blockIdx.x * 4 + (threadIdx.x >> 6);
  int lane = threadIdx.x & 63;
  const float* rp = c2 + (long)row * 128 + lane * 2;
  float acc = rp[0] * w[lane * 2] + rp[1] * w[lane * 2 + 1];
#pragma unroll
  for (int o = 32; o > 0; o >>= 1) acc += __shfl_xor(acc, o, 64);
  if (lane == 0) out[row] = acc + b[0];
}

// ---------------------------------------------------------------------------
extern "C" void kernel_launch(void* const* d_in, const int* in_sizes, int n_in,
                              void* d_out, int out_size, void* d_ws, size_t ws_size,
                              hipStream_t stream)
{
  const float* X    = (const float*)d_in[0];
  const float* c0w  = (const float*)d_in[1];
  const float* d1w  = (const float*)d_in[2];
  const float* d1b  = (const float*)d_in[3];
  const float* p1w  = (const float*)d_in[4];
  const float* p1b  = (const float*)d_in[5];
  const float* g1   = (const float*)d_in[6];
  const float* b1   = (const float*)d_in[7];
  const float* m1   = (const float*)d_in[8];
  const float* v1   = (const float*)d_in[9];
  const float* d2w  = (const float*)d_in[10];
  const float* d2b  = (const float*)d_in[11];
  const float* p2w  = (const float*)d_in[12];
  const float* p2b  = (const float*)d_in[13];
  const float* g2   = (const float*)d_in[14];
  const float* b2   = (const float*)d_in[15];
  const float* m2   = (const float*)d_in[16];
  const float* v2   = (const float*)d_in[17];
  const float* projw= (const float*)d_in[18];
  const float* projb= (const float*)d_in[19];
  const float* ln0g = (const float*)d_in[20];
  const float* ln0b = (const float*)d_in[21];
  const float* pos  = (const float*)d_in[22];
  const float* ln1g = (const float*)d_in[23];
  const float* ln1b = (const float*)d_in[24];
  const float* wq   = (const float*)d_in[25];
  const float* bq   = (const float*)d_in[26];
  const float* wk   = (const float*)d_in[27];
  const float* bk   = (const float*)d_in[28];
  const float* wv   = (const float*)d_in[29];
  const float* bv   = (const float*)d_in[30];
  const float* wo   = (const float*)d_in[31];
  const float* bo   = (const float*)d_in[32];
  const float* pmat = (const float*)d_in[33];
  const float* ln2g = (const float*)d_in[34];
  const float* ln2b = (const float*)d_in[35];
  const float* ffw1 = (const float*)d_in[36];
  const float* ffb1 = (const float*)d_in[37];
  const float* ffw2 = (const float*)d_in[38];
  const float* ffb2 = (const float*)d_in[39];
  const float* cw1  = (const float*)d_in[40];
  const float* cb1  = (const float*)d_in[41];
  const float* clng = (const float*)d_in[42];
  const float* clnb = (const float*)d_in[43];
  const float* cw2  = (const float*)d_in[44];
  const float* cb2  = (const float*)d_in[45];
  (void)in_sizes; (void)n_in; (void)out_size; (void)ws_size;

  // ---- workspace (float-slot offsets); total 22,662,144 fl = 90.6 MB ----
  float* ws     = (float*)d_ws;
  float* x1     = ws;                          // 1,048,576
  float* x2     = ws + 1048576;
  float* lnb32  = ws + 2097152;
  bf16*  lnb16  = (bf16*)(ws + 3145728);       // [4096][256]
  bf16*  hconvb = (bf16*)(ws + 3407872);       // [4096][256]
  // --- transformer scratch inside A1 span [3670016, 20447232) ---
  bf16*  obufb  = (bf16*)(ws + 3670016);       // [4096][256]
  bf16*  qkvb   = (bf16*)(ws + 3932160);       // [4096][768] (cols 512+ unused)
  bf16*  vT     = (bf16*)(ws + 5505024);       // [8][64][2048]
  bf16*  qf     = (bf16*)(ws + 6029312);       // [8][2048][384]
  bf16*  kfT    = (bf16*)(ws + 9175040);       // [8][384][2048]
  float* ctx32  = ws + 12320768;               // [8][64][384] fp32 (196608)
  float* ksum   = ws + 12517376;               // 4096
  float* dinvp  = ws + 12521472;               // 16384
  bf16*  ctxb   = (bf16*)(ws + 12537856);      // [8][64][384] bf16 (49152 fl)
  float* c1     = ws + 12587008;               // classifier [4096][128]
  float* c2     = ws + 13111296;               // [4096][128] -> 13635584
  bf16*  gb2    = (bf16*)(ws + 16633856);      // [4096][1024]
  bf16*  A1     = (bf16*)(ws + 3670016);       // conv-only, 16,777,216 fl span
  // --- converted weights (survive A1; after its span) ---
  bf16*  wqkv_bf= (bf16*)(ws + 20447232);      // [4][768][256]
  float* qkvbias= ws + 20840448;               // [4][768]
  bf16*  f1w_bf = (bf16*)(ws + 20843520);      // [4][2048][256]
  bf16*  f2w_bf = (bf16*)(ws + 21892096);      // [4][256][1024]
  bf16*  wo_bf  = (bf16*)(ws + 22416384);      // [4][256][256]
  bf16*  pm_bf  = (bf16*)(ws + 22547456);      // [4][384][64]
  bf16*  projwT = (bf16*)(ws + 22596608);      // [256][256]
  bf16*  cw1T   = (bf16*)(ws + 22629376);      // [128][256]
  bf16*  pw2_bf = (bf16*)(ws + 22645760);      // [256][128] -> end 22662144
  bf16*  sbuf   = qkvb;                        // classifier reuse

  const float dn = 0.35355339059327378f;  // 64^-0.25

  // --- weight conversion ---
  pack_qkv_kernel<<<3072, 256, 0, stream>>>(wq, wk, wv, wqkv_bf);
  pack_qkvbias_kernel<<<12, 256, 0, stream>>>(bq, bk, bv, qkvbias);
  tconv_kernel<<<dim3(2048, 1, 4), 256, 0, stream>>>(ffw1, f1w_bf, 256, 2048, 524288, 524288);
  tconv_kernel<<<dim3(1024, 1, 4), 256, 0, stream>>>(ffw2, f2w_bf, 1024, 256, 262144, 262144);
  tconv_kernel<<<dim3(256, 1, 4), 256, 0, stream>>>(wo, wo_bf, 256, 256, 65536, 65536);
  tconv_kernel<<<dim3(256, 1, 1), 256, 0, stream>>>(projw, projwT, 256, 256, 65536, 65536);
  tconv_kernel<<<dim3(128, 1, 1), 256, 0, stream>>>(cw1, cw1T, 256, 128, 32768, 32768);
  f2b_kernel<<<384, 256, 0, stream>>>(pmat, pm_bf, 98304);
  f2b_kernel<<<128, 256, 0, stream>>>(p2w, pw2_bf, 32768);

  // --- conv frontend ---
  front1_kernel<<<4096, 256, 0, stream>>>(X, c0w, d1w, d1b, p1w, p1b, g1, b1, m1, v1, A1);
  convtail_kernel<<<4096, 256, 0, stream>>>(A1, d2w, d2b, pw2_bf, p2b, g2, b2, m2, v2, hconvb);

  // proj + ln0 + pos -> x1 = x2
  mgemm_kernel<float, 0><<<dim3(64, 4, 1), 256, 0, stream>>>(
      hconvb, projwT, projb, nullptr, nullptr, lnb32, nullptr,
      256, 256, 256, 256, 0, 0, 0, 0, 0, 0, 0, 0, 1, 1.f);
  ln_kernel<256, false, true, true, float><<<1024, 256, 0, stream>>>(
      lnb32, ln0g, ln0b, pos, x1, x2);

  for (int l = 0; l < 4; ++l) {
    const bf16* wqkv_l = wqkv_bf + (size_t)l * 196608;
    const float* qb_l  = qkvbias + l * 768;
    const bf16* pm_l   = pm_bf + (size_t)l * 24576;
    const bf16* wo_l   = wo_bf + (size_t)l * 65536;
    const float* bov   = bo + l * 256;
    const bf16* f1w_l  = f1w_bf + (size_t)l * 524288;
    const float* f1b_l = ffb1 + l * 2048;
    const bf16* f2w_l  = f2w_bf + (size_t)l * 262144;
    const float* f2b_l = ffb2 + l * 256;

    // a = LN(x2) -> bf16
    ln_kernel<256, false, false, false, bf16><<<1024, 256, 0, stream>>>(
        x2, ln1g + l * 256, ln1b + l * 256, nullptr, lnb16, nullptr);
    // qkv: q,k -> qkvb rows; v -> vT transposed
    mgemm_kernel<bf16, 5><<<dim3(64, 12, 1), 256, 0, stream>>>(
        lnb16, wqkv_l, qb_l, nullptr, nullptr, qkvb, vT,
        256, 256, 256, 768, 0, 0, 0, 0, 0, 0, 0, 0, 1, 1.f);
    // zero ctx32
    zero4_kernel<<<192, 256, 0, stream>>>(ctx32);
    // fused FAVOR: qf (row) + kfT (transposed)
    favor_kernel<<<dim3(32, 6, 16), 256, 0, stream>>>(
        qkvb, pm_l, qf, kfT, dn);
    // ksum (contiguous, no atomics), dinv
    rowsum_kernel<<<dim3(8, 96), 256, 0, stream>>>(kfT, ksum);
    dinv_kernel<<<dim3(8, 512), 256, 0, stream>>>(qf, ksum, dinvp);
    // ctx split-K: 8 segments of 256 over t;  ctx32[z][d][j] += partials
    mgemm_kernel<float, 7><<<dim3(1, 6, 64), 256, 0, stream>>>(
        vT, kfT, nullptr, nullptr, nullptr, ctx32, nullptr,
        256, 2048, 2048, 384, 131072, 256, 786432, 256, 24576, 0, 0, 0, 8, 1.f);
    f2b_kernel<<<768, 256, 0, stream>>>(ctx32, ctxb, 196608);
    // o = (qf @ ctxb^T) * dinv -> obufb [b][t][h*64+d] bf16
    mgemm_kernel<bf16, 3><<<dim3(32, 1, 8), 256, 0, stream>>>(
        qf, ctxb, nullptr, nullptr, dinvp, obufb, nullptr,
        384, 384, 384, 256, 3145728, 786432, 98304, 24576, 524288, 64, 8192, 2048, 4, 1.f);
    // x1 += o @ wo + bo
    mgemm_kernel<float, 1><<<dim3(64, 4, 1), 256, 0, stream>>>(
        obufb, wo_l, bov, x1, nullptr, x1, nullptr,
        256, 256, 256, 256, 0, 0, 0, 0, 0, 0, 0, 0, 1, 1.f);
    // f = LN(x1) -> bf16
    ln_kernel<256, false, false, false, bf16><<<1024, 256, 0, stream>>>(
        x1, ln2g + l * 256, ln2b + l * 256, nullptr, lnb16, nullptr);
    // gb2 = gelu(f@W1a + b1a) * (f@W1b + b1b)   (fused GLU; B2 via sRb)
    mgemm_kernel<bf16, 8><<<dim3(64, 16, 1), 256, 0, stream>>>(
        lnb16, f1w_l, f1b_l, nullptr, nullptr, gb2, nullptr,
        256, 256, 256, 1024, 0, 0, 0, 0, 0, 0, 262144, 0, 1, 1.f);
    // x2 += gb2 @ ffw2 + b
    mgemm_kernel<float, 1><<<dim3(64, 4, 1), 256, 0, stream>>>(
        gb2, f2w_l, f2b_l, x2, nullptr, x2, nullptr,
        1024, 1024, 1024, 256, 0, 0, 0, 0, 0, 0, 0, 0, 1, 1.f);
  }

  // classifier
  sumb_kernel<<<1024, 256, 0, stream>>>(x1, x2, sbuf);
  mgemm_kernel<float, 0><<<dim3(64, 2, 1), 256, 0, stream>>>(
      sbuf, cw1T, cb1, nullptr, nullptr, c1, nullptr,
      256, 256, 256, 128, 0, 0, 0, 0, 0, 0, 0, 0, 1, 1.f);
  ln_kernel<128, true, false, false, float><<<1024, 256, 0, stream>>>(
      c1, clng, clnb, nullptr, c2, nullptr);
  clf2_kernel<<<1024, 256, 0, stream>>>(c2, cw2, cb2, (float*)d_out);
}